// Round 1
// baseline (197.606 us; speedup 1.0000x reference)
//
#include <hip/hip_runtime.h>
#include <math.h>

#define N_PTS   8192
#define ENC     384
#define NTHREAD 384          // == ENC, 6 waves
#define MAXNB   2048         // expected ~59 neighbors, Poisson tail << 2048

__global__ __launch_bounds__(NTHREAD) void vecKM_kernel(
    const float* __restrict__ pts,   // (N, 3) row-major
    const float* __restrict__ A,     // (3, ENC) row-major
    float* __restrict__ out,
    int out_mode)                    // 0: real-only (N,ENC) f32; 1: interleaved re/im
{
    const int i = blockIdx.x;
    const int t = threadIdx.x;

    __shared__ float nb_x[MAXNB];
    __shared__ float nb_y[MAXNB];
    __shared__ float nb_z[MAXNB];
    __shared__ int   nb_cnt;
    __shared__ float red[8];

    if (t == 0) nb_cnt = 0;
    __syncthreads();

    // own point
    const float xi = pts[3 * i + 0];
    const float yi = pts[3 * i + 1];
    const float zi = pts[3 * i + 2];
    const double dxi = (double)xi, dyi = (double)yi, dzi = (double)zi;
    const double R2 = (double)0.12 * (double)0.12;   // matches np float64 threshold

    // ---- Phase 1: neighbor scan (block-uniform loop so ballots are safe) ----
    const int lane = t & 63;
    for (int jb = 0; jb < N_PTS; jb += NTHREAD) {
        const int j = jb + t;
        bool isnb = false;
        float xj = 0.f, yj = 0.f, zj = 0.f;
        if (j < N_PTS) {
            xj = pts[3 * j + 0];
            yj = pts[3 * j + 1];
            zj = pts[3 * j + 2];
            // exact-f64 distance: classification matches the float64 numpy ref
            double dx = (double)xj - dxi;
            double dy = (double)yj - dyi;
            double dz = (double)zj - dzi;
            double d2 = dx * dx + dy * dy + dz * dz;
            isnb = d2 < R2;
        }
        unsigned long long mask = __ballot(isnb);
        if (mask) {
            int leader = __ffsll((long long)mask) - 1;
            int base = 0;
            if (lane == leader) base = atomicAdd(&nb_cnt, __popcll(mask));
            base = __shfl(base, leader);
            if (isnb) {
                int pos = base + __popcll(mask & ((1ull << lane) - 1ull));
                if (pos < MAXNB) {
                    nb_x[pos] = __fdiv_rn(xj, 0.12f);  // store pts/R
                    nb_y[pos] = __fdiv_rn(yj, 0.12f);
                    nb_z[pos] = __fdiv_rn(zj, 0.12f);
                }
            }
        }
    }
    __syncthreads();
    const int nn = min(nb_cnt, MAXNB);

    // ---- Phase 2: thread t owns enc dim k=t; sum cos/sin over neighbors ----
    const float a0 = A[t];
    const float a1 = A[ENC + t];
    const float a2 = A[2 * ENC + t];

    float gr = 0.f, gi = 0.f;
    for (int m = 0; m < nn; ++m) {
        float px = nb_x[m];   // same-address LDS reads: broadcast, conflict-free
        float py = nb_y[m];
        float pz = nb_z[m];
        float pa = fmaf(pz, a2, fmaf(py, a1, px * a0));
        float sv, cv;
        sincosf(pa, &sv, &cv);
        gr += cv;
        gi += sv;
    }

    // own-row phase e^{i pA_i}
    float pxi = __fdiv_rn(xi, 0.12f);
    float pyi = __fdiv_rn(yi, 0.12f);
    float pzi = __fdiv_rn(zi, 0.12f);
    float pai = fmaf(pzi, a2, fmaf(pyi, a1, pxi * a0));
    float si, ci;
    sincosf(pai, &si, &ci);

    // ---- Phase 3: row norm (|G| is phase-invariant), rotate, scale, store ----
    float m2 = fmaf(gr, gr, gi * gi);
    #pragma unroll
    for (int off = 32; off > 0; off >>= 1) m2 += __shfl_down(m2, off);
    const int wave = t >> 6;
    if (lane == 0) red[wave] = m2;
    __syncthreads();
    if (t == 0) {
        float tot = 0.f;
        #pragma unroll
        for (int w = 0; w < NTHREAD / 64; ++w) tot += red[w];
        red[6] = tot;
    }
    __syncthreads();
    const float norm2 = red[6];
    const float scale = sqrtf(384.0f / norm2);

    const float re = (gr * ci + gi * si) * scale;   // Re[(Gr+iGi)(c-is)]
    const float im = (gi * ci - gr * si) * scale;   // Im[(Gr+iGi)(c-is)]

    if (out_mode == 0) {
        out[i * ENC + t] = re;
    } else {
        out[2 * (i * ENC + t) + 0] = re;
        out[2 * (i * ENC + t) + 1] = im;
    }
}

extern "C" void kernel_launch(void* const* d_in, const int* in_sizes, int n_in,
                              void* d_out, int out_size, void* d_ws, size_t ws_size,
                              hipStream_t stream) {
    const float* pts = (const float*)d_in[0];   // (8192, 3) f32
    const float* A   = (const float*)d_in[1];   // (3, 384) f32
    float* out = (float*)d_out;

    // complex64 output may surface as real-part f32 (N*ENC) or interleaved (2*N*ENC)
    const int out_mode = (out_size >= 2 * N_PTS * ENC) ? 1 : 0;

    vecKM_kernel<<<N_PTS, NTHREAD, 0, stream>>>(pts, A, out, out_mode);
}

// Round 2
// 125.112 us; speedup vs baseline: 1.5794x; 1.5794x over previous
//
#include <hip/hip_runtime.h>
#include <math.h>

#define N_PTS   8192
#define ENC     384
#define NTHREAD 384          // == ENC, 6 waves
#define MAXNB   768          // mean ~59 neighbors, Poisson sigma ~7.7 -> 768 is unreachable

__device__ __forceinline__ void fast_sincos(float x, float& s, float& c) {
    // gfx950 v_sin_f32/v_cos_f32 take REVOLUTIONS: D = sin(2*pi*S0).
    // rev error <= |x| * 2^-24 ~ 2.4e-5 rad at |x|~400 — far below tolerance.
    float rev = x * 0.15915494309189535f;   // x / (2*pi)
    rev -= rintf(rev);                      // v_rndne -> rev in [-0.5, 0.5]
    s = __builtin_amdgcn_sinf(rev);
    c = __builtin_amdgcn_cosf(rev);
}

__global__ __launch_bounds__(NTHREAD) void vecKM_kernel(
    const float* __restrict__ pts,   // (N, 3) row-major
    const float* __restrict__ A,     // (3, ENC) row-major
    float* __restrict__ out,
    int out_mode)                    // 0: real-only (N,ENC) f32; 1: interleaved re/im
{
    const int i = blockIdx.x;
    const int t = threadIdx.x;

    __shared__ float nb_x[MAXNB];
    __shared__ float nb_y[MAXNB];
    __shared__ float nb_z[MAXNB];
    __shared__ int   nb_cnt;
    __shared__ float red[8];

    if (t == 0) nb_cnt = 0;
    __syncthreads();

    // own point
    const float xi = pts[3 * i + 0];
    const float yi = pts[3 * i + 1];
    const float zi = pts[3 * i + 2];
    const double dxi = (double)xi, dyi = (double)yi, dzi = (double)zi;
    const double R2  = (double)0.12 * (double)0.12;  // exact threshold (matches np)
    const float  R2F = 0.0144f;
    const float  BAND = 1e-6f;                       // |f32 d2 err| << 1e-6 abs
    const float  R2_LO = R2F - BAND;
    const float  R2_HI = R2F + BAND;

    // ---- Phase 1: neighbor scan (block-uniform loop so ballots are safe) ----
    const int lane = t & 63;
    for (int jb = 0; jb < N_PTS; jb += NTHREAD) {
        const int j = jb + t;
        bool isnb = false;
        float xj = 0.f, yj = 0.f, zj = 0.f;
        if (j < N_PTS) {
            xj = pts[3 * j + 0];
            yj = pts[3 * j + 1];
            zj = pts[3 * j + 2];
            float fdx = xj - xi, fdy = yj - yi, fdz = zj - zi;
            float d2f = fmaf(fdx, fdx, fmaf(fdy, fdy, fdz * fdz));
            if (d2f < R2_LO) {
                isnb = true;
            } else if (d2f <= R2_HI) {
                // borderline (~50 pairs chip-wide): exact f64, identical to R1 classification
                double dx = (double)xj - dxi;
                double dy = (double)yj - dyi;
                double dz = (double)zj - dzi;
                isnb = (dx * dx + dy * dy + dz * dz) < R2;
            }
        }
        unsigned long long mask = __ballot(isnb);
        if (mask) {
            int leader = __ffsll((long long)mask) - 1;
            int base = 0;
            if (lane == leader) base = atomicAdd(&nb_cnt, __popcll(mask));
            base = __shfl(base, leader);
            if (isnb) {
                int pos = base + __popcll(mask & ((1ull << lane) - 1ull));
                if (pos < MAXNB) {
                    nb_x[pos] = __fdiv_rn(xj, 0.12f);  // store pts/R
                    nb_y[pos] = __fdiv_rn(yj, 0.12f);
                    nb_z[pos] = __fdiv_rn(zj, 0.12f);
                }
            }
        }
    }
    __syncthreads();
    const int nn = min(nb_cnt, MAXNB);

    // ---- Phase 2: thread t owns enc dim k=t; sum cos/sin over neighbors ----
    const float a0 = A[t];
    const float a1 = A[ENC + t];
    const float a2 = A[2 * ENC + t];

    float gr = 0.f, gi = 0.f;
    #pragma unroll 4
    for (int m = 0; m < nn; ++m) {
        float px = nb_x[m];   // same-address LDS reads: broadcast, conflict-free
        float py = nb_y[m];
        float pz = nb_z[m];
        float pa = fmaf(pz, a2, fmaf(py, a1, px * a0));
        float sv, cv;
        fast_sincos(pa, sv, cv);
        gr += cv;
        gi += sv;
    }

    // own-row phase e^{i pA_i}
    float pxi = __fdiv_rn(xi, 0.12f);
    float pyi = __fdiv_rn(yi, 0.12f);
    float pzi = __fdiv_rn(zi, 0.12f);
    float pai = fmaf(pzi, a2, fmaf(pyi, a1, pxi * a0));
    float si, ci;
    fast_sincos(pai, si, ci);

    // ---- Phase 3: row norm (|G| is phase-invariant), rotate, scale, store ----
    float m2 = fmaf(gr, gr, gi * gi);
    #pragma unroll
    for (int off = 32; off > 0; off >>= 1) m2 += __shfl_down(m2, off);
    const int wave = t >> 6;
    if (lane == 0) red[wave] = m2;
    __syncthreads();
    if (t == 0) {
        float tot = 0.f;
        #pragma unroll
        for (int w = 0; w < NTHREAD / 64; ++w) tot += red[w];
        red[6] = tot;
    }
    __syncthreads();
    const float norm2 = red[6];
    const float scale = sqrtf(384.0f / norm2);

    const float re = (gr * ci + gi * si) * scale;   // Re[(Gr+iGi)(c-is)]
    const float im = (gi * ci - gr * si) * scale;   // Im[(Gr+iGi)(c-is)]

    if (out_mode == 0) {
        out[i * ENC + t] = re;
    } else {
        out[2 * (i * ENC + t) + 0] = re;
        out[2 * (i * ENC + t) + 1] = im;
    }
}

extern "C" void kernel_launch(void* const* d_in, const int* in_sizes, int n_in,
                              void* d_out, int out_size, void* d_ws, size_t ws_size,
                              hipStream_t stream) {
    const float* pts = (const float*)d_in[0];   // (8192, 3) f32
    const float* A   = (const float*)d_in[1];   // (3, 384) f32
    float* out = (float*)d_out;

    // complex64 output may surface as real-part f32 (N*ENC) or interleaved (2*N*ENC)
    const int out_mode = (out_size >= 2 * N_PTS * ENC) ? 1 : 0;

    vecKM_kernel<<<N_PTS, NTHREAD, 0, stream>>>(pts, A, out, out_mode);
}

// Round 3
// 122.324 us; speedup vs baseline: 1.6154x; 1.0228x over previous
//
#include <hip/hip_runtime.h>
#include <math.h>

#define N_PTS   8192
#define ENC     384
#define NTHREAD 384
#define MAXNB   512
#define NCELL1  8
#define NCELLS  512          // 8^3
#define RADIUS  0.12f

__device__ __forceinline__ void fast_sincos(float x, float& s, float& c) {
    // gfx950 v_sin_f32/v_cos_f32 take REVOLUTIONS. rev err <= |x|*2^-24 — negligible here.
    float rev = x * 0.15915494309189535f;
    rev -= rintf(rev);
    s = __builtin_amdgcn_sinf(rev);
    c = __builtin_amdgcn_cosf(rev);
}

__device__ __forceinline__ int cell_of(float x) {
    int c = (int)(x * 8.0f);
    return min(NCELL1 - 1, max(0, c));
}

// ---------------- ws layout (bytes) ----------------
// ints region:
//   OFF_START  : 520 ints  (cell_start[513] used)
//   OFF_CURSOR : 512 ints
//   OFF_CELLID : 8192 ints
//   OFF_ORIG   : 8192 ints
// then floats:
//   sorted_pts : 8192*3 f32
//   cs         : 8192*384 float2
static const size_t OFF_START_I  = 0;
static const size_t OFF_CURSOR_I = 520;
static const size_t OFF_CELLID_I = 1032;
static const size_t OFF_ORIG_I   = 1032 + 8192;           // 9224
static const size_t INT_REGION_B = (9224 + 8192) * 4;     // 69664 (16B aligned)
static const size_t OFF_SPTS_B   = INT_REGION_B;
static const size_t OFF_CS_B     = 168960;                // 69664+98304=167968 -> round to 1024
static const size_t WS_SMALL_B   = OFF_CS_B;
static const size_t WS_FULL_B    = OFF_CS_B + (size_t)N_PTS * ENC * 2 * 4;  // 25334784

// ---------------- K1: count + scan (single block) ----------------
__global__ __launch_bounds__(1024) void k_count_scan(const float* __restrict__ pts,
                                                     int* __restrict__ cell_id,
                                                     int* __restrict__ cell_start,
                                                     int* __restrict__ cursor) {
    __shared__ int cnt[NCELLS];
    __shared__ int sc[NCELLS];
    const int t = threadIdx.x;
    if (t < NCELLS) cnt[t] = 0;
    __syncthreads();
    for (int i = t; i < N_PTS; i += 1024) {
        int cx = cell_of(pts[3 * i + 0]);
        int cy = cell_of(pts[3 * i + 1]);
        int cz = cell_of(pts[3 * i + 2]);
        int c = (cx * NCELL1 + cy) * NCELL1 + cz;
        cell_id[i] = c;
        atomicAdd(&cnt[c], 1);
    }
    __syncthreads();
    if (t < NCELLS) sc[t] = cnt[t];
    __syncthreads();
    for (int off = 1; off < NCELLS; off <<= 1) {
        int v = 0;
        if (t < NCELLS && t >= off) v = sc[t - off];
        __syncthreads();
        if (t < NCELLS) sc[t] += v;
        __syncthreads();
    }
    if (t < NCELLS) {
        int excl = sc[t] - cnt[t];
        cell_start[t] = excl;
        cursor[t] = excl;
    }
    if (t == 0) cell_start[NCELLS] = N_PTS;
}

// ---------------- K2: scatter into sorted order ----------------
__global__ __launch_bounds__(256) void k_scatter(const float* __restrict__ pts,
                                                 const int* __restrict__ cell_id,
                                                 int* __restrict__ cursor,
                                                 int* __restrict__ orig,
                                                 float* __restrict__ sorted_pts) {
    int i = blockIdx.x * 256 + threadIdx.x;
    if (i >= N_PTS) return;
    int c = cell_id[i];
    int pos = atomicAdd(&cursor[c], 1);
    orig[pos] = i;
    sorted_pts[3 * pos + 0] = pts[3 * i + 0];
    sorted_pts[3 * pos + 1] = pts[3 * i + 1];
    sorted_pts[3 * pos + 2] = pts[3 * i + 2];
}

// ---------------- K3: encode cs[pos][k] = (cos, sin)(A_k . pts/R) ----------------
__global__ __launch_bounds__(NTHREAD) void k_encode(const float* __restrict__ sorted_pts,
                                                    const float* __restrict__ A,
                                                    float2* __restrict__ cs) {
    const int p = blockIdx.x;
    const int t = threadIdx.x;
    float qx = __fdiv_rn(sorted_pts[3 * p + 0], RADIUS);
    float qy = __fdiv_rn(sorted_pts[3 * p + 1], RADIUS);
    float qz = __fdiv_rn(sorted_pts[3 * p + 2], RADIUS);
    float a0 = A[t], a1 = A[ENC + t], a2 = A[2 * ENC + t];
    float pa = fmaf(qz, a2, fmaf(qy, a1, qx * a0));
    float s, c;
    fast_sincos(pa, s, c);
    cs[p * ENC + t] = make_float2(c, s);
}

// ---------------- K4: main — neighbor find + gather/recompute + normalize ----------------
template <bool USE_CS>
__global__ __launch_bounds__(NTHREAD) void k_main(const float* __restrict__ sorted_pts,
                                                  const int* __restrict__ orig,
                                                  const int* __restrict__ cell_start,
                                                  const float2* __restrict__ cs,
                                                  const float* __restrict__ A,
                                                  float* __restrict__ out, int out_mode) {
    // chunked XCD swizzle: consecutive sorted points land on the same XCD L2
    const int p = (blockIdx.x % 8) * (N_PTS / 8) + blockIdx.x / 8;
    const int t = threadIdx.x, lane = t & 63, wid = t >> 6;

    __shared__ int   nb_idx[MAXNB];
    __shared__ float nb_dx[MAXNB], nb_dy[MAXNB], nb_dz[MAXNB];
    __shared__ int   nb_cnt;
    __shared__ float red[8];
    if (t == 0) nb_cnt = 0;
    __syncthreads();

    const float xi = sorted_pts[3 * p + 0];
    const float yi = sorted_pts[3 * p + 1];
    const float zi = sorted_pts[3 * p + 2];
    const double dxi = (double)xi, dyi = (double)yi, dzi = (double)zi;
    const double R2  = (double)0.12 * (double)0.12;
    const float  R2_LO = 0.0144f - 1e-6f;
    const float  R2_HI = 0.0144f + 1e-6f;

    const int cx = cell_of(xi), cy = cell_of(yi), cz = cell_of(zi);
    const int zlo = max(cz - 1, 0), zhi = min(cz + 1, NCELL1 - 1);

    for (int r = wid; r < 9; r += NTHREAD / 64) {
        int cxx = cx + (r / 3) - 1;
        int cyy = cy + (r % 3) - 1;
        if (cxx < 0 || cxx >= NCELL1 || cyy < 0 || cyy >= NCELL1) continue;
        int base_c = (cxx * NCELL1 + cyy) * NCELL1;
        int lo = cell_start[base_c + zlo];
        int hi = cell_start[base_c + zhi + 1];
        for (int jb = lo; jb < hi; jb += 64) {
            int j = jb + lane;
            bool isnb = false;
            float xj = 0.f, yj = 0.f, zj = 0.f;
            if (j < hi) {
                xj = sorted_pts[3 * j + 0];
                yj = sorted_pts[3 * j + 1];
                zj = sorted_pts[3 * j + 2];
                float fdx = xj - xi, fdy = yj - yi, fdz = zj - zi;
                float d2f = fmaf(fdx, fdx, fmaf(fdy, fdy, fdz * fdz));
                if (d2f < R2_LO) {
                    isnb = true;
                } else if (d2f <= R2_HI) {
                    double ddx = (double)xj - dxi, ddy = (double)yj - dyi, ddz = (double)zj - dzi;
                    isnb = (ddx * ddx + ddy * ddy + ddz * ddz) < R2;
                }
            }
            unsigned long long mask = __ballot(isnb);
            if (mask) {
                int leader = __ffsll((long long)mask) - 1;
                int basep = 0;
                if (lane == leader) basep = atomicAdd(&nb_cnt, __popcll(mask));
                basep = __shfl(basep, leader);
                if (isnb) {
                    int pos = basep + __popcll(mask & ((1ull << lane) - 1ull));
                    if (pos < MAXNB) {
                        nb_idx[pos] = j;
                        if (!USE_CS) {
                            nb_dx[pos] = (xj - xi) * (1.0f / 0.12f);
                            nb_dy[pos] = (yj - yi) * (1.0f / 0.12f);
                            nb_dz[pos] = (zj - zi) * (1.0f / 0.12f);
                        }
                    }
                }
            }
        }
    }
    __syncthreads();
    const int nn = min(nb_cnt, MAXNB);

    float gr = 0.f, gi = 0.f;
    float ci, si;
    if (USE_CS) {
        const float2* row0 = cs + t;
        #pragma unroll 4
        for (int m = 0; m < nn; ++m) {
            int j = nb_idx[m];
            float2 v = row0[j * ENC];   // coalesced 512B per wave per neighbor
            gr += v.x;
            gi += v.y;
        }
        float2 own = cs[p * ENC + t];
        ci = own.x; si = own.y;
    } else {
        float a0 = A[t], a1 = A[ENC + t], a2 = A[2 * ENC + t];
        for (int m = 0; m < nn; ++m) {
            float pa = fmaf(nb_dz[m], a2, fmaf(nb_dy[m], a1, nb_dx[m] * a0));
            float sv, cv;
            fast_sincos(pa, sv, cv);
            gr += cv;
            gi += sv;
        }
        ci = 1.f; si = 0.f;   // angles already relative to own point -> phase pre-divided
    }

    // row norm (phase-invariant), rotate by conj(own), scale, store
    float m2 = fmaf(gr, gr, gi * gi);
    #pragma unroll
    for (int off = 32; off > 0; off >>= 1) m2 += __shfl_down(m2, off);
    if (lane == 0) red[wid] = m2;
    __syncthreads();
    if (t == 0) {
        float tot = 0.f;
        #pragma unroll
        for (int w = 0; w < NTHREAD / 64; ++w) tot += red[w];
        red[7] = tot;
    }
    __syncthreads();
    const float scale = sqrtf(384.0f / red[7]);

    const float re = (gr * ci + gi * si) * scale;
    const float im = (gi * ci - gr * si) * scale;

    const int o = orig[p];
    if (out_mode == 0) {
        out[o * ENC + t] = re;
    } else {
        ((float2*)out)[o * ENC + t] = make_float2(re, im);
    }
}

// ---------------- last-resort all-pairs (R2 kernel) ----------------
__global__ __launch_bounds__(NTHREAD) void vecKM_allpairs(const float* __restrict__ pts,
                                                          const float* __restrict__ A,
                                                          float* __restrict__ out, int out_mode) {
    const int i = blockIdx.x;
    const int t = threadIdx.x;
    __shared__ float nb_x[MAXNB], nb_y[MAXNB], nb_z[MAXNB];
    __shared__ int nb_cnt;
    __shared__ float red[8];
    if (t == 0) nb_cnt = 0;
    __syncthreads();
    const float xi = pts[3 * i + 0], yi = pts[3 * i + 1], zi = pts[3 * i + 2];
    const double dxi = xi, dyi = yi, dzi = zi;
    const double R2 = (double)0.12 * (double)0.12;
    const float R2_LO = 0.0144f - 1e-6f, R2_HI = 0.0144f + 1e-6f;
    const int lane = t & 63;
    for (int jb = 0; jb < N_PTS; jb += NTHREAD) {
        const int j = jb + t;
        bool isnb = false;
        float xj = 0.f, yj = 0.f, zj = 0.f;
        if (j < N_PTS) {
            xj = pts[3 * j + 0]; yj = pts[3 * j + 1]; zj = pts[3 * j + 2];
            float fdx = xj - xi, fdy = yj - yi, fdz = zj - zi;
            float d2f = fmaf(fdx, fdx, fmaf(fdy, fdy, fdz * fdz));
            if (d2f < R2_LO) isnb = true;
            else if (d2f <= R2_HI) {
                double dx = (double)xj - dxi, dy = (double)yj - dyi, dz = (double)zj - dzi;
                isnb = (dx * dx + dy * dy + dz * dz) < R2;
            }
        }
        unsigned long long mask = __ballot(isnb);
        if (mask) {
            int leader = __ffsll((long long)mask) - 1;
            int basep = 0;
            if (lane == leader) basep = atomicAdd(&nb_cnt, __popcll(mask));
            basep = __shfl(basep, leader);
            if (isnb) {
                int pos = basep + __popcll(mask & ((1ull << lane) - 1ull));
                if (pos < MAXNB) {
                    nb_x[pos] = (xj - xi) * (1.0f / 0.12f);
                    nb_y[pos] = (yj - yi) * (1.0f / 0.12f);
                    nb_z[pos] = (zj - zi) * (1.0f / 0.12f);
                }
            }
        }
    }
    __syncthreads();
    const int nn = min(nb_cnt, MAXNB);
    const float a0 = A[t], a1 = A[ENC + t], a2 = A[2 * ENC + t];
    float gr = 0.f, gi = 0.f;
    #pragma unroll 4
    for (int m = 0; m < nn; ++m) {
        float pa = fmaf(nb_z[m], a2, fmaf(nb_y[m], a1, nb_x[m] * a0));
        float sv, cv;
        fast_sincos(pa, sv, cv);
        gr += cv; gi += sv;
    }
    float m2 = fmaf(gr, gr, gi * gi);
    #pragma unroll
    for (int off = 32; off > 0; off >>= 1) m2 += __shfl_down(m2, off);
    const int wid = t >> 6;
    if (lane == 0) red[wid] = m2;
    __syncthreads();
    if (t == 0) {
        float tot = 0.f;
        for (int w = 0; w < NTHREAD / 64; ++w) tot += red[w];
        red[7] = tot;
    }
    __syncthreads();
    const float scale = sqrtf(384.0f / red[7]);
    const float re = gr * scale, im = gi * scale;  // angles relative: already phase-divided
    if (out_mode == 0) out[i * ENC + t] = re;
    else ((float2*)out)[i * ENC + t] = make_float2(re, im);
}

extern "C" void kernel_launch(void* const* d_in, const int* in_sizes, int n_in,
                              void* d_out, int out_size, void* d_ws, size_t ws_size,
                              hipStream_t stream) {
    const float* pts = (const float*)d_in[0];
    const float* A   = (const float*)d_in[1];
    float* out = (float*)d_out;
    const int out_mode = (out_size >= 2 * N_PTS * ENC) ? 1 : 0;

    if (ws_size >= WS_SMALL_B) {
        int*   wsi        = (int*)d_ws;
        int*   cell_start = wsi + OFF_START_I;
        int*   cursor     = wsi + OFF_CURSOR_I;
        int*   cell_id    = wsi + OFF_CELLID_I;
        int*   orig       = wsi + OFF_ORIG_I;
        float* sorted_pts = (float*)((char*)d_ws + OFF_SPTS_B);

        k_count_scan<<<1, 1024, 0, stream>>>(pts, cell_id, cell_start, cursor);
        k_scatter<<<(N_PTS + 255) / 256, 256, 0, stream>>>(pts, cell_id, cursor, orig, sorted_pts);

        if (ws_size >= WS_FULL_B) {
            float2* cs = (float2*)((char*)d_ws + OFF_CS_B);
            k_encode<<<N_PTS, NTHREAD, 0, stream>>>(sorted_pts, A, cs);
            k_main<true><<<N_PTS, NTHREAD, 0, stream>>>(sorted_pts, orig, cell_start, cs, A, out, out_mode);
        } else {
            k_main<false><<<N_PTS, NTHREAD, 0, stream>>>(sorted_pts, orig, cell_start, nullptr, A, out, out_mode);
        }
    } else {
        vecKM_allpairs<<<N_PTS, NTHREAD, 0, stream>>>(pts, A, out, out_mode);
    }
}

// Round 5
// 77.500 us; speedup vs baseline: 2.5498x; 1.5784x over previous
//
#include <hip/hip_runtime.h>
#include <hip/hip_fp16.h>
#include <math.h>

#define N_PTS   8192
#define ENC     384
#define NTHREAD 384
#define MAXNB   512
#define NCELL1  8
#define NCELLS  512
#define RADIUS  0.12f

__device__ __forceinline__ void fast_sincos(float x, float& s, float& c) {
    // gfx950 v_sin/v_cos take REVOLUTIONS. rev err <= |x|*2^-24 — negligible here.
    float rev = x * 0.15915494309189535f;
    rev -= rintf(rev);
    s = __builtin_amdgcn_sinf(rev);
    c = __builtin_amdgcn_cosf(rev);
}

__device__ __forceinline__ int cell_of(float x) {
    int c = (int)(x * 8.0f);
    return min(NCELL1 - 1, max(0, c));
}

// ---------------- ws layout (bytes) ----------------
static const size_t OFF_START_I  = 0;          // 520 ints (cell_start[513])
static const size_t OFF_CURSOR_I = 520;        // 512 ints
static const size_t OFF_CELLID_I = 1032;       // 8192 ints
static const size_t OFF_ORIG_I   = 9224;       // 8192 ints
static const size_t INT_REGION_B = 17416u * 4; // 69664
static const size_t OFF_SPTS_B   = INT_REGION_B;            // float4[8192] = 131072 B
static const size_t OFF_CS_B     = OFF_SPTS_B + 131072;     // 200736 (16B aligned)
// cs: (N_PTS+1) rows x 384 dims x (c,s) halves = 8193*1536 B (row 8192 = zero dummy)
static const size_t WS_FULL_B    = OFF_CS_B + (size_t)(N_PTS + 1) * ENC * 2 * 2; // ~12.8 MB
static const size_t WS_SMALL_B   = OFF_CS_B;

// ---------------- K1: count + scan (single block) ----------------
__global__ __launch_bounds__(1024) void k_count_scan(const float* __restrict__ pts,
                                                     int* __restrict__ cell_id,
                                                     int* __restrict__ cell_start,
                                                     int* __restrict__ cursor) {
    __shared__ int cnt[NCELLS];
    __shared__ int sc[NCELLS];
    const int t = threadIdx.x;
    if (t < NCELLS) cnt[t] = 0;
    __syncthreads();
    for (int i = t; i < N_PTS; i += 1024) {
        int cx = cell_of(pts[3 * i + 0]);
        int cy = cell_of(pts[3 * i + 1]);
        int cz = cell_of(pts[3 * i + 2]);
        int c = (cx * NCELL1 + cy) * NCELL1 + cz;
        cell_id[i] = c;
        atomicAdd(&cnt[c], 1);
    }
    __syncthreads();
    if (t < NCELLS) sc[t] = cnt[t];
    __syncthreads();
    for (int off = 1; off < NCELLS; off <<= 1) {
        int v = 0;
        if (t < NCELLS && t >= off) v = sc[t - off];
        __syncthreads();
        if (t < NCELLS) sc[t] += v;
        __syncthreads();
    }
    if (t < NCELLS) {
        int excl = sc[t] - cnt[t];
        cell_start[t] = excl;
        cursor[t] = excl;
    }
    if (t == 0) cell_start[NCELLS] = N_PTS;
}

// ---------------- K2: scatter into cell-sorted order (float4) ----------------
__global__ __launch_bounds__(256) void k_scatter(const float* __restrict__ pts,
                                                 const int* __restrict__ cell_id,
                                                 int* __restrict__ cursor,
                                                 int* __restrict__ orig,
                                                 float4* __restrict__ spts) {
    int i = blockIdx.x * 256 + threadIdx.x;
    if (i >= N_PTS) return;
    int c = cell_id[i];
    int pos = atomicAdd(&cursor[c], 1);
    orig[pos] = i;
    spts[pos] = make_float4(pts[3 * i + 0], pts[3 * i + 1], pts[3 * i + 2], 0.f);
}

// ---------------- K3: cs[pos][k] = (cos,sin) in fp16; row N_PTS zeroed ----------------
__global__ __launch_bounds__(NTHREAD) void k_encode(const float4* __restrict__ spts,
                                                    const float* __restrict__ A,
                                                    __half2* __restrict__ cs) {
    const int p = blockIdx.x;
    const int t = threadIdx.x;
    if (p == N_PTS) {                       // dummy zero row for padded gather
        cs[(size_t)p * ENC + t] = __floats2half2_rn(0.f, 0.f);
        return;
    }
    float4 P = spts[p];
    float qx = __fdiv_rn(P.x, RADIUS);
    float qy = __fdiv_rn(P.y, RADIUS);
    float qz = __fdiv_rn(P.z, RADIUS);
    float a0 = A[t], a1 = A[ENC + t], a2 = A[2 * ENC + t];
    float pa = fmaf(qz, a2, fmaf(qy, a1, qx * a0));
    float s, c;
    fast_sincos(pa, s, c);
    cs[(size_t)p * ENC + t] = __floats2half2_rn(c, s);
}

// ---------------- K4: main — neighbor find + wide fp16 gather + normalize ----------------
__global__ __launch_bounds__(NTHREAD) void k_main(const float4* __restrict__ spts,
                                                  const int* __restrict__ orig,
                                                  const int* __restrict__ cell_start,
                                                  const uint4* __restrict__ cs4,  // row = 96 uint4
                                                  const float* __restrict__ A,
                                                  float* __restrict__ out, int out_mode) {
    // chunked XCD swizzle: consecutive sorted points share an XCD's L2 window
    const int p = (blockIdx.x % 8) * (N_PTS / 8) + blockIdx.x / 8;
    const int t = threadIdx.x, lane = t & 63, wid = t >> 6;

    __shared__ unsigned short nb_idx[MAXNB];
    __shared__ int   nb_cnt;
    __shared__ float comb_a[96][8];
    __shared__ float comb_b[96][8];
    __shared__ float red2[96];
    __shared__ float red_tot;
    if (t == 0) nb_cnt = 0;
    __syncthreads();

    const float4 Pi = spts[p];
    const float xi = Pi.x, yi = Pi.y, zi = Pi.z;
    const double dxi = (double)xi, dyi = (double)yi, dzi = (double)zi;
    const double R2 = (double)0.12 * (double)0.12;
    const float R2_LO = 0.0144f - 1e-6f;
    const float R2_HI = 0.0144f + 1e-6f;

    const int cx = cell_of(xi), cy = cell_of(yi), cz = cell_of(zi);
    const int zlo = max(cz - 1, 0), zhi = min(cz + 1, NCELL1 - 1);

    // ---- Phase 1: candidate scan over 3x3 cell columns (classification == R3) ----
    for (int r = wid; r < 9; r += NTHREAD / 64) {
        int cxx = cx + (r / 3) - 1;
        int cyy = cy + (r % 3) - 1;
        if (cxx < 0 || cxx >= NCELL1 || cyy < 0 || cyy >= NCELL1) continue;
        int base_c = (cxx * NCELL1 + cyy) * NCELL1;
        int lo = cell_start[base_c + zlo];
        int hi = cell_start[base_c + zhi + 1];
        for (int jb = lo; jb < hi; jb += 64) {
            int j = jb + lane;
            bool isnb = false;
            if (j < hi) {
                float4 Pj = spts[j];
                float fdx = Pj.x - xi, fdy = Pj.y - yi, fdz = Pj.z - zi;
                float d2f = fmaf(fdx, fdx, fmaf(fdy, fdy, fdz * fdz));
                if (d2f < R2_LO) {
                    isnb = true;
                } else if (d2f <= R2_HI) {
                    double ddx = (double)Pj.x - dxi, ddy = (double)Pj.y - dyi, ddz = (double)Pj.z - dzi;
                    isnb = (ddx * ddx + ddy * ddy + ddz * ddz) < R2;
                }
            }
            unsigned long long mask = __ballot(isnb);
            if (mask) {
                int leader = __ffsll((long long)mask) - 1;
                int basep = 0;
                if (lane == leader) basep = atomicAdd(&nb_cnt, __popcll(mask));
                basep = __shfl(basep, leader);
                if (isnb) {
                    int pos = basep + __popcll(mask & ((1ull << lane) - 1ull));
                    if (pos < MAXNB) nb_idx[pos] = (unsigned short)j;
                }
            }
        }
    }
    __syncthreads();
    const int nn = min(nb_cnt, MAXNB);
    if (t < 4) {                       // dummy-pad so the gather loop is branch-free
        int idx = nn + t;
        if (idx < MAXNB) nb_idx[idx] = (unsigned short)N_PTS;
    }
    __syncthreads();
    const int nn_pad = (nn + 3) & ~3;

    // ---- Phase 2: group g handles neighbor m+g; q covers dims 4q..4q+3 (16B) ----
    const int g = t / 96, q = t - g * 96;
    float4 accR = make_float4(0.f, 0.f, 0.f, 0.f);
    float4 accI = make_float4(0.f, 0.f, 0.f, 0.f);

    #pragma unroll 4
    for (int m = 0; m < nn_pad; m += 4) {
        int j = min((int)nb_idx[m + g], N_PTS);
        uint4 u = cs4[j * 96 + q];     // FIX: row stride is 96 uint4 (1536 B), not 48
        float2 f0 = __half22float2(*reinterpret_cast<__half2*>(&u.x));
        float2 f1 = __half22float2(*reinterpret_cast<__half2*>(&u.y));
        float2 f2 = __half22float2(*reinterpret_cast<__half2*>(&u.z));
        float2 f3 = __half22float2(*reinterpret_cast<__half2*>(&u.w));
        accR.x += f0.x; accI.x += f0.y;
        accR.y += f1.x; accI.y += f1.y;
        accR.z += f2.x; accI.z += f2.y;
        accR.w += f3.x; accI.w += f3.y;
    }

    // ---- combine the 4 neighbor-groups onto g==0 ----
    if (g == 1) {
        float* d = comb_a[q];
        d[0]=accR.x; d[1]=accR.y; d[2]=accR.z; d[3]=accR.w;
        d[4]=accI.x; d[5]=accI.y; d[6]=accI.z; d[7]=accI.w;
    } else if (g == 3) {
        float* d = comb_b[q];
        d[0]=accR.x; d[1]=accR.y; d[2]=accR.z; d[3]=accR.w;
        d[4]=accI.x; d[5]=accI.y; d[6]=accI.z; d[7]=accI.w;
    }
    __syncthreads();
    if (g == 0) {
        const float* s = comb_a[q];
        accR.x+=s[0]; accR.y+=s[1]; accR.z+=s[2]; accR.w+=s[3];
        accI.x+=s[4]; accI.y+=s[5]; accI.z+=s[6]; accI.w+=s[7];
    } else if (g == 2) {
        const float* s = comb_b[q];
        accR.x+=s[0]; accR.y+=s[1]; accR.z+=s[2]; accR.w+=s[3];
        accI.x+=s[4]; accI.y+=s[5]; accI.z+=s[6]; accI.w+=s[7];
    }
    __syncthreads();
    if (g == 2) {
        float* d = comb_a[q];
        d[0]=accR.x; d[1]=accR.y; d[2]=accR.z; d[3]=accR.w;
        d[4]=accI.x; d[5]=accI.y; d[6]=accI.z; d[7]=accI.w;
    }
    __syncthreads();
    if (g == 0) {
        const float* s = comb_a[q];
        accR.x+=s[0]; accR.y+=s[1]; accR.z+=s[2]; accR.w+=s[3];
        accI.x+=s[4]; accI.y+=s[5]; accI.z+=s[6]; accI.w+=s[7];
    }

    // ---- Phase 3: norm (phase-invariant), rotate by conj(own), scale, store ----
    if (g == 0) {
        float m2 = accR.x*accR.x + accI.x*accI.x + accR.y*accR.y + accI.y*accI.y
                 + accR.z*accR.z + accI.z*accI.z + accR.w*accR.w + accI.w*accI.w;
        red2[q] = m2;
    }
    __syncthreads();
    if (t < 64) {
        float v = red2[t] + (t < 32 ? red2[64 + t] : 0.f);
        #pragma unroll
        for (int off = 32; off > 0; off >>= 1) v += __shfl_down(v, off);
        if (t == 0) red_tot = v;
    }
    __syncthreads();

    if (g == 0) {
        const float scale = sqrtf(384.0f / red_tot);
        const float qx = __fdiv_rn(xi, RADIUS);
        const float qy = __fdiv_rn(yi, RADIUS);
        const float qz = __fdiv_rn(zi, RADIUS);
        const int d0 = 4 * q;
        float re[4], im[4];
        #pragma unroll
        for (int k = 0; k < 4; ++k) {
            int d = d0 + k;
            float pa = fmaf(qz, A[2 * ENC + d], fmaf(qy, A[ENC + d], qx * A[d]));
            float sv, cv;
            fast_sincos(pa, sv, cv);
            float gr = (k==0)?accR.x:(k==1)?accR.y:(k==2)?accR.z:accR.w;
            float gi = (k==0)?accI.x:(k==1)?accI.y:(k==2)?accI.z:accI.w;
            re[k] = (gr * cv + gi * sv) * scale;
            im[k] = (gi * cv - gr * sv) * scale;
        }
        const int o = orig[p];
        if (out_mode == 0) {
            ((float4*)out)[o * 96 + q] = make_float4(re[0], re[1], re[2], re[3]);
        } else {
            ((float4*)out)[o * 192 + 2 * q + 0] = make_float4(re[0], im[0], re[1], im[1]);
            ((float4*)out)[o * 192 + 2 * q + 1] = make_float4(re[2], im[2], re[3], im[3]);
        }
    }
}

// ---------------- last-resort all-pairs (ws too small; effectively dead) ----------------
__global__ __launch_bounds__(NTHREAD) void vecKM_allpairs(const float* __restrict__ pts,
                                                          const float* __restrict__ A,
                                                          float* __restrict__ out, int out_mode) {
    const int i = blockIdx.x;
    const int t = threadIdx.x;
    __shared__ float nb_x[MAXNB], nb_y[MAXNB], nb_z[MAXNB];
    __shared__ int nb_cnt;
    __shared__ float red[8];
    if (t == 0) nb_cnt = 0;
    __syncthreads();
    const float xi = pts[3 * i + 0], yi = pts[3 * i + 1], zi = pts[3 * i + 2];
    const double dxi = xi, dyi = yi, dzi = zi;
    const double R2 = (double)0.12 * (double)0.12;
    const float R2_LO = 0.0144f - 1e-6f, R2_HI = 0.0144f + 1e-6f;
    const int lane = t & 63;
    for (int jb = 0; jb < N_PTS; jb += NTHREAD) {
        const int j = jb + t;
        bool isnb = false;
        float xj = 0.f, yj = 0.f, zj = 0.f;
        if (j < N_PTS) {
            xj = pts[3 * j + 0]; yj = pts[3 * j + 1]; zj = pts[3 * j + 2];
            float fdx = xj - xi, fdy = yj - yi, fdz = zj - zi;
            float d2f = fmaf(fdx, fdx, fmaf(fdy, fdy, fdz * fdz));
            if (d2f < R2_LO) isnb = true;
            else if (d2f <= R2_HI) {
                double dx = (double)xj - dxi, dy = (double)yj - dyi, dz = (double)zj - dzi;
                isnb = (dx * dx + dy * dy + dz * dz) < R2;
            }
        }
        unsigned long long mask = __ballot(isnb);
        if (mask) {
            int leader = __ffsll((long long)mask) - 1;
            int basep = 0;
            if (lane == leader) basep = atomicAdd(&nb_cnt, __popcll(mask));
            basep = __shfl(basep, leader);
            if (isnb) {
                int pos = basep + __popcll(mask & ((1ull << lane) - 1ull));
                if (pos < MAXNB) {
                    nb_x[pos] = (xj - xi) * (1.0f / 0.12f);
                    nb_y[pos] = (yj - yi) * (1.0f / 0.12f);
                    nb_z[pos] = (zj - zi) * (1.0f / 0.12f);
                }
            }
        }
    }
    __syncthreads();
    const int nn = min(nb_cnt, MAXNB);
    const float a0 = A[t], a1 = A[ENC + t], a2 = A[2 * ENC + t];
    float gr = 0.f, gi = 0.f;
    #pragma unroll 4
    for (int m = 0; m < nn; ++m) {
        float pa = fmaf(nb_z[m], a2, fmaf(nb_y[m], a1, nb_x[m] * a0));
        float sv, cv;
        fast_sincos(pa, sv, cv);
        gr += cv; gi += sv;
    }
    float m2 = fmaf(gr, gr, gi * gi);
    #pragma unroll
    for (int off = 32; off > 0; off >>= 1) m2 += __shfl_down(m2, off);
    const int wid = t >> 6;
    if (lane == 0) red[wid] = m2;
    __syncthreads();
    if (t == 0) {
        float tot = 0.f;
        for (int w = 0; w < NTHREAD / 64; ++w) tot += red[w];
        red[7] = tot;
    }
    __syncthreads();
    const float scale = sqrtf(384.0f / red[7]);
    const float re = gr * scale, im = gi * scale;
    if (out_mode == 0) out[i * ENC + t] = re;
    else ((float2*)out)[i * ENC + t] = make_float2(re, im);
}

extern "C" void kernel_launch(void* const* d_in, const int* in_sizes, int n_in,
                              void* d_out, int out_size, void* d_ws, size_t ws_size,
                              hipStream_t stream) {
    const float* pts = (const float*)d_in[0];
    const float* A   = (const float*)d_in[1];
    float* out = (float*)d_out;
    const int out_mode = (out_size >= 2 * N_PTS * ENC) ? 1 : 0;

    if (ws_size >= WS_FULL_B) {
        int*    wsi        = (int*)d_ws;
        int*    cell_start = wsi + OFF_START_I;
        int*    cursor     = wsi + OFF_CURSOR_I;
        int*    cell_id    = wsi + OFF_CELLID_I;
        int*    orig       = wsi + OFF_ORIG_I;
        float4* spts       = (float4*)((char*)d_ws + OFF_SPTS_B);
        __half2* cs        = (__half2*)((char*)d_ws + OFF_CS_B);

        k_count_scan<<<1, 1024, 0, stream>>>(pts, cell_id, cell_start, cursor);
        k_scatter<<<(N_PTS + 255) / 256, 256, 0, stream>>>(pts, cell_id, cursor, orig, spts);
        k_encode<<<N_PTS + 1, NTHREAD, 0, stream>>>(spts, A, cs);
        k_main<<<N_PTS, NTHREAD, 0, stream>>>(spts, orig, cell_start,
                                              (const uint4*)cs, A, out, out_mode);
    } else {
        vecKM_allpairs<<<N_PTS, NTHREAD, 0, stream>>>(pts, A, out, out_mode);
    }
}

// Round 6
// 74.366 us; speedup vs baseline: 2.6572x; 1.0421x over previous
//
#include <hip/hip_runtime.h>
#include <hip/hip_fp16.h>
#include <math.h>

#define N_PTS   8192
#define ENC     384
#define NTHREAD 384
#define MAXNB   512
#define NCELL1  8
#define NCELLS  512
#define RADIUS  0.12f

__device__ __forceinline__ void fast_sincos(float x, float& s, float& c) {
    // gfx950 v_sin/v_cos take REVOLUTIONS. rev err <= |x|*2^-24 — negligible here.
    float rev = x * 0.15915494309189535f;
    rev -= rintf(rev);
    s = __builtin_amdgcn_sinf(rev);
    c = __builtin_amdgcn_cosf(rev);
}

__device__ __forceinline__ int cell_of(float x) {
    int c = (int)(x * 8.0f);
    return min(NCELL1 - 1, max(0, c));
}

// ---------------- ws layout (bytes) ----------------
static const size_t OFF_START_I  = 0;          // 520 ints (cell_start[513])
static const size_t OFF_CURSOR_I = 520;        // 512 ints
static const size_t OFF_CELLID_I = 1032;       // 8192 ints
static const size_t OFF_ORIG_I   = 9224;       // 8192 ints
static const size_t INT_REGION_B = 17416u * 4; // 69664
static const size_t OFF_SPTS_B   = INT_REGION_B;            // float4[8192] = 131072 B
static const size_t OFF_CS_B     = OFF_SPTS_B + 131072;     // 200736 (16B aligned)
// cs: (N_PTS+1) rows x 384 dims x (c,s) halves = 8193*1536 B (row 8192 = zero dummy)
static const size_t WS_FULL_B    = OFF_CS_B + (size_t)(N_PTS + 1) * ENC * 2 * 2; // ~12.8 MB

// ---------------- K1: count + scan (single block) ----------------
__global__ __launch_bounds__(1024) void k_count_scan(const float* __restrict__ pts,
                                                     int* __restrict__ cell_id,
                                                     int* __restrict__ cell_start,
                                                     int* __restrict__ cursor) {
    __shared__ int cnt[NCELLS];
    __shared__ int sc[NCELLS];
    const int t = threadIdx.x;
    if (t < NCELLS) cnt[t] = 0;
    __syncthreads();
    for (int i = t; i < N_PTS; i += 1024) {
        int cx = cell_of(pts[3 * i + 0]);
        int cy = cell_of(pts[3 * i + 1]);
        int cz = cell_of(pts[3 * i + 2]);
        int c = (cx * NCELL1 + cy) * NCELL1 + cz;
        cell_id[i] = c;
        atomicAdd(&cnt[c], 1);
    }
    __syncthreads();
    if (t < NCELLS) sc[t] = cnt[t];
    __syncthreads();
    for (int off = 1; off < NCELLS; off <<= 1) {
        int v = 0;
        if (t < NCELLS && t >= off) v = sc[t - off];
        __syncthreads();
        if (t < NCELLS) sc[t] += v;
        __syncthreads();
    }
    if (t < NCELLS) {
        int excl = sc[t] - cnt[t];
        cell_start[t] = excl;
        cursor[t] = excl;
    }
    if (t == 0) cell_start[NCELLS] = N_PTS;
}

// ---------------- K2: scatter into cell-sorted order (float4) ----------------
__global__ __launch_bounds__(256) void k_scatter(const float* __restrict__ pts,
                                                 const int* __restrict__ cell_id,
                                                 int* __restrict__ cursor,
                                                 int* __restrict__ orig,
                                                 float4* __restrict__ spts) {
    int i = blockIdx.x * 256 + threadIdx.x;
    if (i >= N_PTS) return;
    int c = cell_id[i];
    int pos = atomicAdd(&cursor[c], 1);
    orig[pos] = i;
    spts[pos] = make_float4(pts[3 * i + 0], pts[3 * i + 1], pts[3 * i + 2], 0.f);
}

// ---------------- K3: cs[pos][k] = (cos,sin) in fp16; row N_PTS zeroed ----------------
__global__ __launch_bounds__(NTHREAD) void k_encode(const float4* __restrict__ spts,
                                                    const float* __restrict__ A,
                                                    __half2* __restrict__ cs) {
    const int p = blockIdx.x;
    const int t = threadIdx.x;
    if (p == N_PTS) {                       // dummy zero row for padded gather
        cs[(size_t)p * ENC + t] = __floats2half2_rn(0.f, 0.f);
        return;
    }
    float4 P = spts[p];
    float qx = __fdiv_rn(P.x, RADIUS);
    float qy = __fdiv_rn(P.y, RADIUS);
    float qz = __fdiv_rn(P.z, RADIUS);
    float a0 = A[t], a1 = A[ENC + t], a2 = A[2 * ENC + t];
    float pa = fmaf(qz, a2, fmaf(qy, a1, qx * a0));
    float s, c;
    fast_sincos(pa, s, c);
    cs[(size_t)p * ENC + t] = __floats2half2_rn(c, s);
}

// ---------------- K4: main — neighbor find + packed-fp16 gather + normalize ----------------
__global__ __launch_bounds__(NTHREAD) void k_main(const float4* __restrict__ spts,
                                                  const int* __restrict__ orig,
                                                  const int* __restrict__ cell_start,
                                                  const uint4* __restrict__ cs4,  // row = 96 uint4
                                                  const float* __restrict__ A,
                                                  float* __restrict__ out, int out_mode) {
    // chunked XCD swizzle: consecutive sorted points share an XCD's L2 window
    const int p = (blockIdx.x % 8) * (N_PTS / 8) + blockIdx.x / 8;
    const int t = threadIdx.x, lane = t & 63, wid = t >> 6;

    // transposed index store: group g's index sequence is contiguous -> ds_read_b128 x8
    __shared__ __align__(16) unsigned short nb_idx_g[4][MAXNB / 4];
    __shared__ int   nb_cnt;
    __shared__ float comb_a[96][8];
    __shared__ float comb_b[96][8];
    __shared__ float red2[96];
    __shared__ float red_tot;
    if (t == 0) nb_cnt = 0;
    __syncthreads();

    const float4 Pi = spts[p];
    const float xi = Pi.x, yi = Pi.y, zi = Pi.z;
    const double dxi = (double)xi, dyi = (double)yi, dzi = (double)zi;
    const double R2 = (double)0.12 * (double)0.12;
    const float R2_LO = 0.0144f - 1e-6f;
    const float R2_HI = 0.0144f + 1e-6f;

    const int cx = cell_of(xi), cy = cell_of(yi), cz = cell_of(zi);
    const int zlo = max(cz - 1, 0), zhi = min(cz + 1, NCELL1 - 1);

    // ---- Phase 1: candidate scan over 3x3 cell columns (classification == R5) ----
    for (int r = wid; r < 9; r += NTHREAD / 64) {
        int cxx = cx + (r / 3) - 1;
        int cyy = cy + (r % 3) - 1;
        if (cxx < 0 || cxx >= NCELL1 || cyy < 0 || cyy >= NCELL1) continue;
        int base_c = (cxx * NCELL1 + cyy) * NCELL1;
        int lo = cell_start[base_c + zlo];
        int hi = cell_start[base_c + zhi + 1];
        for (int jb = lo; jb < hi; jb += 64) {
            int j = jb + lane;
            bool isnb = false;
            if (j < hi) {
                float4 Pj = spts[j];
                float fdx = Pj.x - xi, fdy = Pj.y - yi, fdz = Pj.z - zi;
                float d2f = fmaf(fdx, fdx, fmaf(fdy, fdy, fdz * fdz));
                if (d2f < R2_LO) {
                    isnb = true;
                } else if (d2f <= R2_HI) {
                    double ddx = (double)Pj.x - dxi, ddy = (double)Pj.y - dyi, ddz = (double)Pj.z - dzi;
                    isnb = (ddx * ddx + ddy * ddy + ddz * ddz) < R2;
                }
            }
            unsigned long long mask = __ballot(isnb);
            if (mask) {
                int leader = __ffsll((long long)mask) - 1;
                int basep = 0;
                if (lane == leader) basep = atomicAdd(&nb_cnt, __popcll(mask));
                basep = __shfl(basep, leader);
                if (isnb) {
                    int pos = basep + __popcll(mask & ((1ull << lane) - 1ull));
                    if (pos < MAXNB) nb_idx_g[pos & 3][pos >> 2] = (unsigned short)j;
                }
            }
        }
    }
    __syncthreads();
    const int nn = min(nb_cnt, MAXNB);
    const int P8 = ((((nn + 3) >> 2) + 7) & ~7);   // per-group count, padded to x8
    {
        int npad = 4 * P8 - nn;                    // <= 34
        if (t < npad) {
            int s = nn + t;
            nb_idx_g[s & 3][s >> 2] = (unsigned short)N_PTS;   // dummy zero row
        }
    }
    __syncthreads();

    // ---- Phase 2: group g takes neighbors pos%4==g; q covers dims 4q..4q+3 ----
    const int g = t / 96, q = t - g * 96;
    const uint4* cs_q = cs4 + q;

    __half2 ac0 = __float2half2_rn(0.f);
    __half2 ac1 = ac0, ac2 = ac0, ac3 = ac0;

    for (int mb = 0; mb < P8; mb += 8) {
        uint4 iv = *reinterpret_cast<const uint4*>(&nb_idx_g[g][mb]);  // 8 u16 indices
        int j0 = (int)(iv.x & 0xFFFFu), j1 = (int)(iv.x >> 16);
        int j2 = (int)(iv.y & 0xFFFFu), j3 = (int)(iv.y >> 16);
        int j4 = (int)(iv.z & 0xFFFFu), j5 = (int)(iv.z >> 16);
        int j6 = (int)(iv.w & 0xFFFFu), j7 = (int)(iv.w >> 16);
        uint4 u0 = cs_q[min(j0, N_PTS) * 96];
        uint4 u1 = cs_q[min(j1, N_PTS) * 96];
        uint4 u2 = cs_q[min(j2, N_PTS) * 96];
        uint4 u3 = cs_q[min(j3, N_PTS) * 96];
        uint4 u4 = cs_q[min(j4, N_PTS) * 96];
        uint4 u5 = cs_q[min(j5, N_PTS) * 96];
        uint4 u6 = cs_q[min(j6, N_PTS) * 96];
        uint4 u7 = cs_q[min(j7, N_PTS) * 96];
        #define ACC(U) \
            ac0 = __hadd2(ac0, *reinterpret_cast<const __half2*>(&U.x)); \
            ac1 = __hadd2(ac1, *reinterpret_cast<const __half2*>(&U.y)); \
            ac2 = __hadd2(ac2, *reinterpret_cast<const __half2*>(&U.z)); \
            ac3 = __hadd2(ac3, *reinterpret_cast<const __half2*>(&U.w));
        ACC(u0) ACC(u1) ACC(u2) ACC(u3) ACC(u4) ACC(u5) ACC(u6) ACC(u7)
        #undef ACC
    }

    float2 f0 = __half22float2(ac0);
    float2 f1 = __half22float2(ac1);
    float2 f2 = __half22float2(ac2);
    float2 f3 = __half22float2(ac3);
    float4 accR = make_float4(f0.x, f1.x, f2.x, f3.x);
    float4 accI = make_float4(f0.y, f1.y, f2.y, f3.y);

    // ---- combine the 4 neighbor-groups onto g==0 (f32) ----
    if (g == 1) {
        float* d = comb_a[q];
        d[0]=accR.x; d[1]=accR.y; d[2]=accR.z; d[3]=accR.w;
        d[4]=accI.x; d[5]=accI.y; d[6]=accI.z; d[7]=accI.w;
    } else if (g == 3) {
        float* d = comb_b[q];
        d[0]=accR.x; d[1]=accR.y; d[2]=accR.z; d[3]=accR.w;
        d[4]=accI.x; d[5]=accI.y; d[6]=accI.z; d[7]=accI.w;
    }
    __syncthreads();
    if (g == 0) {
        const float* s = comb_a[q];
        accR.x+=s[0]; accR.y+=s[1]; accR.z+=s[2]; accR.w+=s[3];
        accI.x+=s[4]; accI.y+=s[5]; accI.z+=s[6]; accI.w+=s[7];
    } else if (g == 2) {
        const float* s = comb_b[q];
        accR.x+=s[0]; accR.y+=s[1]; accR.z+=s[2]; accR.w+=s[3];
        accI.x+=s[4]; accI.y+=s[5]; accI.z+=s[6]; accI.w+=s[7];
    }
    __syncthreads();
    if (g == 2) {
        float* d = comb_a[q];
        d[0]=accR.x; d[1]=accR.y; d[2]=accR.z; d[3]=accR.w;
        d[4]=accI.x; d[5]=accI.y; d[6]=accI.z; d[7]=accI.w;
    }
    __syncthreads();
    if (g == 0) {
        const float* s = comb_a[q];
        accR.x+=s[0]; accR.y+=s[1]; accR.z+=s[2]; accR.w+=s[3];
        accI.x+=s[4]; accI.y+=s[5]; accI.z+=s[6]; accI.w+=s[7];
    }

    // ---- Phase 3: norm (phase-invariant), rotate by conj(own), scale, store ----
    if (g == 0) {
        float m2 = accR.x*accR.x + accI.x*accI.x + accR.y*accR.y + accI.y*accI.y
                 + accR.z*accR.z + accI.z*accI.z + accR.w*accR.w + accI.w*accI.w;
        red2[q] = m2;
    }
    __syncthreads();
    if (t < 64) {
        float v = red2[t] + (t < 32 ? red2[64 + t] : 0.f);
        #pragma unroll
        for (int off = 32; off > 0; off >>= 1) v += __shfl_down(v, off);
        if (t == 0) red_tot = v;
    }
    __syncthreads();

    if (g == 0) {
        const float scale = sqrtf(384.0f / red_tot);
        const float qx = __fdiv_rn(xi, RADIUS);
        const float qy = __fdiv_rn(yi, RADIUS);
        const float qz = __fdiv_rn(zi, RADIUS);
        const int d0 = 4 * q;
        float re[4], im[4];
        #pragma unroll
        for (int k = 0; k < 4; ++k) {
            int d = d0 + k;
            float pa = fmaf(qz, A[2 * ENC + d], fmaf(qy, A[ENC + d], qx * A[d]));
            float sv, cv;
            fast_sincos(pa, sv, cv);
            float gr = (k==0)?accR.x:(k==1)?accR.y:(k==2)?accR.z:accR.w;
            float gi = (k==0)?accI.x:(k==1)?accI.y:(k==2)?accI.z:accI.w;
            re[k] = (gr * cv + gi * sv) * scale;
            im[k] = (gi * cv - gr * sv) * scale;
        }
        const int o = orig[p];
        if (out_mode == 0) {
            ((float4*)out)[o * 96 + q] = make_float4(re[0], re[1], re[2], re[3]);
        } else {
            ((float4*)out)[o * 192 + 2 * q + 0] = make_float4(re[0], im[0], re[1], im[1]);
            ((float4*)out)[o * 192 + 2 * q + 1] = make_float4(re[2], im[2], re[3], im[3]);
        }
    }
}

// ---------------- last-resort all-pairs (ws too small; effectively dead) ----------------
__global__ __launch_bounds__(NTHREAD) void vecKM_allpairs(const float* __restrict__ pts,
                                                          const float* __restrict__ A,
                                                          float* __restrict__ out, int out_mode) {
    const int i = blockIdx.x;
    const int t = threadIdx.x;
    __shared__ float nb_x[MAXNB], nb_y[MAXNB], nb_z[MAXNB];
    __shared__ int nb_cnt;
    __shared__ float red[8];
    if (t == 0) nb_cnt = 0;
    __syncthreads();
    const float xi = pts[3 * i + 0], yi = pts[3 * i + 1], zi = pts[3 * i + 2];
    const double dxi = xi, dyi = yi, dzi = zi;
    const double R2 = (double)0.12 * (double)0.12;
    const float R2_LO = 0.0144f - 1e-6f, R2_HI = 0.0144f + 1e-6f;
    const int lane = t & 63;
    for (int jb = 0; jb < N_PTS; jb += NTHREAD) {
        const int j = jb + t;
        bool isnb = false;
        float xj = 0.f, yj = 0.f, zj = 0.f;
        if (j < N_PTS) {
            xj = pts[3 * j + 0]; yj = pts[3 * j + 1]; zj = pts[3 * j + 2];
            float fdx = xj - xi, fdy = yj - yi, fdz = zj - zi;
            float d2f = fmaf(fdx, fdx, fmaf(fdy, fdy, fdz * fdz));
            if (d2f < R2_LO) isnb = true;
            else if (d2f <= R2_HI) {
                double dx = (double)xj - dxi, dy = (double)yj - dyi, dz = (double)zj - dzi;
                isnb = (dx * dx + dy * dy + dz * dz) < R2;
            }
        }
        unsigned long long mask = __ballot(isnb);
        if (mask) {
            int leader = __ffsll((long long)mask) - 1;
            int basep = 0;
            if (lane == leader) basep = atomicAdd(&nb_cnt, __popcll(mask));
            basep = __shfl(basep, leader);
            if (isnb) {
                int pos = basep + __popcll(mask & ((1ull << lane) - 1ull));
                if (pos < MAXNB) {
                    nb_x[pos] = (xj - xi) * (1.0f / 0.12f);
                    nb_y[pos] = (yj - yi) * (1.0f / 0.12f);
                    nb_z[pos] = (zj - zi) * (1.0f / 0.12f);
                }
            }
        }
    }
    __syncthreads();
    const int nn = min(nb_cnt, MAXNB);
    const float a0 = A[t], a1 = A[ENC + t], a2 = A[2 * ENC + t];
    float gr = 0.f, gi = 0.f;
    #pragma unroll 4
    for (int m = 0; m < nn; ++m) {
        float pa = fmaf(nb_z[m], a2, fmaf(nb_y[m], a1, nb_x[m] * a0));
        float sv, cv;
        fast_sincos(pa, sv, cv);
        gr += cv; gi += sv;
    }
    float m2 = fmaf(gr, gr, gi * gi);
    #pragma unroll
    for (int off = 32; off > 0; off >>= 1) m2 += __shfl_down(m2, off);
    const int wid = t >> 6;
    if (lane == 0) red[wid] = m2;
    __syncthreads();
    if (t == 0) {
        float tot = 0.f;
        for (int w = 0; w < NTHREAD / 64; ++w) tot += red[w];
        red[7] = tot;
    }
    __syncthreads();
    const float scale = sqrtf(384.0f / red[7]);
    const float re = gr * scale, im = gi * scale;
    if (out_mode == 0) out[i * ENC + t] = re;
    else ((float2*)out)[i * ENC + t] = make_float2(re, im);
}

extern "C" void kernel_launch(void* const* d_in, const int* in_sizes, int n_in,
                              void* d_out, int out_size, void* d_ws, size_t ws_size,
                              hipStream_t stream) {
    const float* pts = (const float*)d_in[0];
    const float* A   = (const float*)d_in[1];
    float* out = (float*)d_out;
    const int out_mode = (out_size >= 2 * N_PTS * ENC) ? 1 : 0;

    if (ws_size >= WS_FULL_B) {
        int*    wsi        = (int*)d_ws;
        int*    cell_start = wsi + OFF_START_I;
        int*    cursor     = wsi + OFF_CURSOR_I;
        int*    cell_id    = wsi + OFF_CELLID_I;
        int*    orig       = wsi + OFF_ORIG_I;
        float4* spts       = (float4*)((char*)d_ws + OFF_SPTS_B);
        __half2* cs        = (__half2*)((char*)d_ws + OFF_CS_B);

        k_count_scan<<<1, 1024, 0, stream>>>(pts, cell_id, cell_start, cursor);
        k_scatter<<<(N_PTS + 255) / 256, 256, 0, stream>>>(pts, cell_id, cursor, orig, spts);
        k_encode<<<N_PTS + 1, NTHREAD, 0, stream>>>(spts, A, cs);
        k_main<<<N_PTS, NTHREAD, 0, stream>>>(spts, orig, cell_start,
                                              (const uint4*)cs, A, out, out_mode);
    } else {
        vecKM_allpairs<<<N_PTS, NTHREAD, 0, stream>>>(pts, A, out, out_mode);
    }
}